// Round 3
// baseline (492.652 us; speedup 1.0000x reference)
//
#include <hip/hip_runtime.h>

#define N_EXPERTS 48
#define D_IN 163840
#define D_OUT 2
#define BATCH 512
#define SPLIT 8
#define CHUNK (D_IN / SPLIT)         // 20480 elements per block
#define THREADS 256
#define ITERS (CHUNK / 4 / THREADS)  // 20 float4 iterations per thread

// Write bias[(t-1) mod 48] into out — out is poisoned 0xAA before every call,
// so this must be a plain store (the dot kernel then atomicAdds partials).
__global__ void init_out_kernel(const int* __restrict__ t,
                                const float* __restrict__ b,
                                float* __restrict__ out) {
    int i = blockIdx.x * blockDim.x + threadIdx.x;   // over BATCH*D_OUT
    if (i < BATCH * D_OUT) {
        int s = i >> 1;
        int k = i & 1;
        int e = (t[s] + N_EXPERTS - 1) % N_EXPERTS;  // (t-1) with wraparound
        out[i] = b[e * D_OUT + k];
    }
}

__global__ __launch_bounds__(THREADS) void moe_dot_kernel(
        const float* __restrict__ x,
        const int* __restrict__ t,
        const float* __restrict__ W,
        float* __restrict__ out) {
    const int chunk  = blockIdx.x;   // 0..SPLIT-1  (fast dim: contiguous addresses)
    const int sample = blockIdx.y;   // 0..BATCH-1

    const int e = (t[sample] + N_EXPERTS - 1) % N_EXPERTS;

    // x chunk base: sample row + chunk offset
    const float4* __restrict__ xp =
        (const float4*)(x + (size_t)sample * D_IN + (size_t)chunk * CHUNK);
    // W slab: [D_IN][2] interleaved — element d occupies floats [2d, 2d+2)
    const float4* __restrict__ wp =
        (const float4*)(W + (size_t)e * D_IN * D_OUT + (size_t)chunk * CHUNK * D_OUT);

    float acc0 = 0.f, acc1 = 0.f;

#pragma unroll
    for (int it = 0; it < ITERS; ++it) {
        const int i = it * THREADS + threadIdx.x;
        float4 xv = xp[i];
        float4 w0 = wp[2 * i];       // (W[d][0], W[d][1], W[d+1][0], W[d+1][1])
        float4 w1 = wp[2 * i + 1];   // (W[d+2][0], W[d+2][1], W[d+3][0], W[d+3][1])
        acc0 += xv.x * w0.x + xv.y * w0.z + xv.z * w1.x + xv.w * w1.z;
        acc1 += xv.x * w0.y + xv.y * w0.w + xv.z * w1.y + xv.w * w1.w;
    }

    // Wave-level butterfly reduction (64 lanes)
    for (int off = 32; off > 0; off >>= 1) {
        acc0 += __shfl_down(acc0, off);
        acc1 += __shfl_down(acc1, off);
    }

    // Block reduction across 4 waves via LDS
    __shared__ float s0[THREADS / 64];
    __shared__ float s1[THREADS / 64];
    const int wid  = threadIdx.x >> 6;
    const int lane = threadIdx.x & 63;
    if (lane == 0) { s0[wid] = acc0; s1[wid] = acc1; }
    __syncthreads();

    if (threadIdx.x == 0) {
        float a0 = s0[0] + s0[1] + s0[2] + s0[3];
        float a1 = s1[0] + s1[1] + s1[2] + s1[3];
        atomicAdd(&out[sample * D_OUT + 0], a0);
        atomicAdd(&out[sample * D_OUT + 1], a1);
    }
}

extern "C" void kernel_launch(void* const* d_in, const int* in_sizes, int n_in,
                              void* d_out, int out_size, void* d_ws, size_t ws_size,
                              hipStream_t stream) {
    const float* x = (const float*)d_in[0];   // [512, 2,1280,8,8] = [512, 163840]
    const int*   t = (const int*)d_in[1];     // [512]
    const float* W = (const float*)d_in[2];   // [48, 163840, 2]
    const float* b = (const float*)d_in[3];   // [48, 2]
    float* out = (float*)d_out;               // [512, 2]

    // 1) out = bias[(t-1)%48]
    init_out_kernel<<<(BATCH * D_OUT + THREADS - 1) / THREADS, THREADS, 0, stream>>>(
        t, b, out);

    // 2) out += per-chunk partial dots
    dim3 grid(SPLIT, BATCH);
    moe_dot_kernel<<<grid, THREADS, 0, stream>>>(x, t, W, out);
}

// Round 8
// 480.778 us; speedup vs baseline: 1.0247x; 1.0247x over previous
//
#include <hip/hip_runtime.h>

#define N_EXPERTS 48
#define D_IN 163840
#define D_OUT 2
#define BATCH 512
#define SPLIT 8
#define CHUNK (D_IN / SPLIT)         // 20480 elements per block
#define THREADS 256
#define ITERS (CHUNK / 4 / THREADS)  // 20 float4 iterations per thread

// clang-native float4 so __builtin_nontemporal_load accepts the pointer
// (HIP_vector_type<float,4>* is rejected — round-7 compile error).
typedef float nfloat4 __attribute__((ext_vector_type(4)));

// ---------------------------------------------------------------------------
// Pass 0: bucket-sort the 512 samples by expert, in ONE block.
// ws layout (ints): [0..511] = sample id in expert-sorted order,
//                   [512..1023] = that sample's expert id.
// Rank within expert comes from the LDS histogram atomicAdd return value;
// intra-expert order is nondeterministic but the result set is identical.
// ---------------------------------------------------------------------------
__global__ __launch_bounds__(BATCH) void bucket_kernel(const int* __restrict__ t,
                                                       int* __restrict__ ws) {
    __shared__ int cnt[N_EXPERTS];
    __shared__ int off[N_EXPERTS];
    const int s = threadIdx.x;            // one thread per sample
    if (s < N_EXPERTS) cnt[s] = 0;
    __syncthreads();
    const int e = (t[s] + N_EXPERTS - 1) % N_EXPERTS;   // (t-1) floor-mod 48
    const int rank = atomicAdd(&cnt[e], 1);
    __syncthreads();
    if (s == 0) {
        int acc = 0;
        for (int i = 0; i < N_EXPERTS; ++i) { off[i] = acc; acc += cnt[i]; }
    }
    __syncthreads();
    const int slot = off[e] + rank;
    ws[slot] = s;
    ws[BATCH + slot] = e;
}

// Write bias[(t-1) mod 48] into out — out is poisoned 0xAA before every call,
// so this must be a plain store (the dot kernel then atomicAdds partials).
__global__ void init_out_kernel(const int* __restrict__ t,
                                const float* __restrict__ b,
                                float* __restrict__ out) {
    int i = blockIdx.x * blockDim.x + threadIdx.x;   // over BATCH*D_OUT
    if (i < BATCH * D_OUT) {
        int s = i >> 1;
        int k = i & 1;
        int e = (t[s] + N_EXPERTS - 1) % N_EXPERTS;
        out[i] = b[e * D_OUT + k];
    }
}

// ---------------------------------------------------------------------------
// Pass 1: per-(chunk, sorted-slot) partial dot.
// grid(SPLIT, BATCH): linear bid = y*8 + chunk → XCD = bid % 8 = chunk, so
// each XCD owns one K-chunk; sorted slots make same-expert blocks temporally
// adjacent on that XCD → the 160 KB (expert,chunk) W region stays L2-hot.
// x is read once globally → nontemporal, don't evict W from L2.
// ---------------------------------------------------------------------------
__global__ __launch_bounds__(THREADS) void moe_dot_kernel(
        const float* __restrict__ x,
        const int* __restrict__ ws,
        const float* __restrict__ W,
        float* __restrict__ out) {
    const int chunk = blockIdx.x;        // 0..SPLIT-1
    const int slot  = blockIdx.y;        // 0..BATCH-1 (expert-sorted)
    const int sample = ws[slot];
    const int e      = ws[BATCH + slot];

    const nfloat4* __restrict__ xp =
        (const nfloat4*)(x + (size_t)sample * D_IN + (size_t)chunk * CHUNK);
    // W slab: [D_IN][2] interleaved — element d occupies floats [2d, 2d+2)
    const float4* __restrict__ wp =
        (const float4*)(W + (size_t)e * D_IN * D_OUT + (size_t)chunk * CHUNK * D_OUT);

    float acc0 = 0.f, acc1 = 0.f;

#pragma unroll 4
    for (int it = 0; it < ITERS; ++it) {
        const int i = it * THREADS + threadIdx.x;
        nfloat4 xv = __builtin_nontemporal_load(&xp[i]);  // streamed, no reuse
        float4 w0 = wp[2 * i];       // (W[d][0], W[d][1], W[d+1][0], W[d+1][1])
        float4 w1 = wp[2 * i + 1];   // (W[d+2][0], W[d+2][1], W[d+3][0], W[d+3][1])
        acc0 += xv.x * w0.x + xv.y * w0.z + xv.z * w1.x + xv.w * w1.z;
        acc1 += xv.x * w0.y + xv.y * w0.w + xv.z * w1.y + xv.w * w1.w;
    }

    // Wave-level butterfly reduction (64 lanes)
    for (int off = 32; off > 0; off >>= 1) {
        acc0 += __shfl_down(acc0, off);
        acc1 += __shfl_down(acc1, off);
    }

    // Block reduction across 4 waves via LDS
    __shared__ float s0[THREADS / 64];
    __shared__ float s1[THREADS / 64];
    const int wid  = threadIdx.x >> 6;
    const int lane = threadIdx.x & 63;
    if (lane == 0) { s0[wid] = acc0; s1[wid] = acc1; }
    __syncthreads();

    if (threadIdx.x == 0) {
        float a0 = s0[0] + s0[1] + s0[2] + s0[3];
        float a1 = s1[0] + s1[1] + s1[2] + s1[3];
        atomicAdd(&out[sample * D_OUT + 0], a0);
        atomicAdd(&out[sample * D_OUT + 1], a1);
    }
}

extern "C" void kernel_launch(void* const* d_in, const int* in_sizes, int n_in,
                              void* d_out, int out_size, void* d_ws, size_t ws_size,
                              hipStream_t stream) {
    const float* x = (const float*)d_in[0];   // [512, 163840]
    const int*   t = (const int*)d_in[1];     // [512]
    const float* W = (const float*)d_in[2];   // [48, 163840, 2]
    const float* b = (const float*)d_in[3];   // [48, 2]
    float* out = (float*)d_out;               // [512, 2]
    int* ws = (int*)d_ws;

    // 0) expert-sort the samples (one tiny block)
    bucket_kernel<<<1, BATCH, 0, stream>>>(t, ws);

    // 1) out = bias[(t-1)%48]
    init_out_kernel<<<(BATCH * D_OUT + THREADS - 1) / THREADS, THREADS, 0, stream>>>(
        t, b, out);

    // 2) out += per-chunk partial dots, expert-sorted block order
    dim3 grid(SPLIT, BATCH);
    moe_dot_kernel<<<grid, THREADS, 0, stream>>>(x, ws, W, out);
}